// Round 5
// baseline (1151.793 us; speedup 1.0000x reference)
//
#include <hip/hip_runtime.h>

typedef _Float16 f16;
typedef _Float16 f16x8 __attribute__((ext_vector_type(8)));
typedef _Float16 f16x4 __attribute__((ext_vector_type(4)));
typedef float f32x4 __attribute__((ext_vector_type(4)));
typedef float f32x16 __attribute__((ext_vector_type(16)));

#define LOG2E 1.44269504088896340736f
#define SOFF  36.0f   // fixed softmax offset (log2 domain); cancels in sum(Pv)/sum(P)
#define CDIM 256
#define NPIX 4096

union Q4 { f16x4 h4; unsigned int u[2]; };
union B8 { f16x8 h8; unsigned int u[4]; };

// async global->LDS 16B copy: lds dest = wave-uniform base + lane*16 (HW rule)
__device__ __forceinline__ void gl2lds16(const f16* g, const f16* l) {
    __builtin_amdgcn_global_load_lds((const __attribute__((address_space(1))) unsigned int*)g,
                                     (__attribute__((address_space(3))) unsigned int*)l, 16, 0, 0);
}

// C-layout quad -> B/A-frag half exchange via lane^32 (verified round 3/4 in attn P path)
__device__ __forceinline__ f16x8 quad_exchange(const Q4* oq, int ksl, int hi) {
    int sidx = 2 * ksl + 1 - hi;
    int oidx = 2 * ksl + hi;
    unsigned int s0 = oq[sidx].u[0], s1 = oq[sidx].u[1];
    unsigned int r0 = (unsigned int)__shfl_xor((int)s0, 32);
    unsigned int r1 = (unsigned int)__shfl_xor((int)s1, 32);
    B8 bb;
    bb.u[0] = hi ? r0 : oq[oidx].u[0];
    bb.u[1] = hi ? r1 : oq[oidx].u[1];
    bb.u[2] = hi ? oq[oidx].u[0] : r0;
    bb.u[3] = hi ? oq[oidx].u[1] : r1;
    return bb.h8;
}

// ---------------- kernel 0: weights fp32 -> fp16 (Wq folded with log2e) ----------------
__global__ void convert_w_kernel(const float* __restrict__ Wq, const float* __restrict__ Wk,
                                 const float* __restrict__ Wv,
                                 f16* __restrict__ Wq_h, f16* __restrict__ Wk_h,
                                 f16* __restrict__ Wv_h) {
    int i = blockIdx.x * 256 + threadIdx.x;   // 65536 elements each
    Wq_h[i] = (f16)(Wq[i] * LOG2E);
    Wk_h[i] = (f16)Wk[i];
    Wv_h[i] = (f16)Wv[i];
}

// ---------------- kernel 1: q/k/v projections, LDS-free, frag-ordered Q/K output ------
// qTf/kTf layout: [b][tile32][ks 0..15][lane 0..63][8 f16]  (1 KB per frag, fully
// coalesced 16B/lane stores & loads). lane = hi*32+l31: l31 = pixel-in-tile (m/n dim),
// hi = k-half; frag ks covers cin/ c = 16ks+8hi+e. vW: [b][c][pixel] fp16 as before.
__global__ __launch_bounds__(256, 2)
void proj_kernel(const float* __restrict__ x, const float* __restrict__ attr,
                 const f16* __restrict__ Wq_h, const float* __restrict__ bq,
                 const f16* __restrict__ Wk_h, const float* __restrict__ bk,
                 const f16* __restrict__ Wv_h, const float* __restrict__ bv,
                 f16* __restrict__ qTf, f16* __restrict__ kTf, f16* __restrict__ vW) {
    const int b  = blockIdx.x & 7;
    const int i0 = (blockIdx.x >> 3) * 64;
    const int t  = threadIdx.x;
    const int w = t >> 6, lane = t & 63, l31 = lane & 31, hi = lane >> 5;
    const int h  = w & 1;           // which 32-pixel half this wave owns
    const int cg = w >> 1;          // which 4-ct group (c-out slabs)
    const int px = i0 + 32 * h + l31;        // pixel this lane owns (n-dim)
    const int it = (i0 >> 5) + h;            // global 32-pixel tile index

    // ---- Q phase: B-frags from x (registers only) ----
    {
        f16x8 xa[16];
        const float* xb = x + (size_t)b * CDIM * NPIX + (size_t)(8 * hi) * NPIX + px;
#pragma unroll
        for (int ks = 0; ks < 16; ++ks) {
            f16x8 v;
#pragma unroll
            for (int e = 0; e < 8; ++e) v[e] = (f16)xb[(size_t)(16 * ks + e) * NPIX];
            xa[ks] = v;
        }
#pragma unroll 1
        for (int c4 = 0; c4 < 4; ++c4) {
            const int ct = cg * 4 + c4;
            const f16* ap = Wq_h + (size_t)(ct * 32 + l31) * CDIM + 8 * hi;
            f32x16 acc;
#pragma unroll
            for (int r = 0; r < 16; ++r) acc[r] = 0.0f;
#pragma unroll
            for (int ks = 0; ks < 16; ++ks)
                acc = __builtin_amdgcn_mfma_f32_32x32x16_f16(*(const f16x8*)(ap + ks * 16), xa[ks], acc, 0, 0, 0);
            Q4 oq[4];
#pragma unroll
            for (int g = 0; g < 4; ++g) {
                f32x4 bb = *(const f32x4*)(bq + ct * 32 + 4 * hi + 8 * g);
#pragma unroll
                for (int e = 0; e < 4; ++e) oq[g].h4[e] = (f16)(acc[4 * g + e] + bb[e] * LOG2E);
            }
#pragma unroll
            for (int ksl = 0; ksl < 2; ++ksl) {
                f16* dst = qTf + ((size_t)(b * 128 + it) * 16 + ct * 2 + ksl) * 512 + lane * 8;
                *(f16x8*)dst = quad_exchange(oq, ksl, hi);
            }
        }
    }

    // ---- K + V phase: B-frags from attr ----
    {
        f16x8 aa[16];
        const float* ab = attr + (size_t)b * CDIM * NPIX + (size_t)(8 * hi) * NPIX + px;
#pragma unroll
        for (int ks = 0; ks < 16; ++ks) {
            f16x8 v;
#pragma unroll
            for (int e = 0; e < 8; ++e) v[e] = (f16)ab[(size_t)(16 * ks + e) * NPIX];
            aa[ks] = v;
        }
        // K tiles -> frag-ordered
#pragma unroll 1
        for (int c4 = 0; c4 < 4; ++c4) {
            const int ct = cg * 4 + c4;
            const f16* ap = Wk_h + (size_t)(ct * 32 + l31) * CDIM + 8 * hi;
            f32x16 acc;
#pragma unroll
            for (int r = 0; r < 16; ++r) acc[r] = 0.0f;
#pragma unroll
            for (int ks = 0; ks < 16; ++ks)
                acc = __builtin_amdgcn_mfma_f32_32x32x16_f16(*(const f16x8*)(ap + ks * 16), aa[ks], acc, 0, 0, 0);
            Q4 oq[4];
#pragma unroll
            for (int g = 0; g < 4; ++g) {
                f32x4 bb = *(const f32x4*)(bk + ct * 32 + 4 * hi + 8 * g);
#pragma unroll
                for (int e = 0; e < 4; ++e) oq[g].h4[e] = (f16)(acc[4 * g + e] + bb[e]);
            }
#pragma unroll
            for (int ksl = 0; ksl < 2; ++ksl) {
                f16* dst = kTf + ((size_t)(b * 128 + it) * 16 + ct * 2 + ksl) * 512 + lane * 8;
                *(f16x8*)dst = quad_exchange(oq, ksl, hi);
            }
        }
        // V tiles -> [c][pixel] (coalesced across lanes)
#pragma unroll 1
        for (int c4 = 0; c4 < 4; ++c4) {
            const int ct = cg * 4 + c4;
            const f16* ap = Wv_h + (size_t)(ct * 32 + l31) * CDIM + 8 * hi;
            f32x16 acc;
#pragma unroll
            for (int r = 0; r < 16; ++r) acc[r] = 0.0f;
#pragma unroll
            for (int ks = 0; ks < 16; ++ks)
                acc = __builtin_amdgcn_mfma_f32_32x32x16_f16(*(const f16x8*)(ap + ks * 16), aa[ks], acc, 0, 0, 0);
            f16* dst = vW + (size_t)b * CDIM * NPIX + px;
#pragma unroll
            for (int g = 0; g < 4; ++g) {
                f32x4 bb = *(const f32x4*)(bv + ct * 32 + 4 * hi + 8 * g);
#pragma unroll
                for (int e = 0; e < 4; ++e) {
                    int c = ct * 32 + 4 * hi + 8 * g + e;
                    dst[(size_t)c * NPIX] = (f16)(acc[4 * g + e] + bb[e]);
                }
            }
        }
    }
}

// ---------------- kernel 2: flash attention + residual ----------------
// 512 threads = 8 waves = 4 i-strips x 2 j-halves; grid 256 = 1 block/CU.
// Q-frags: loaded once from qTf (coalesced). K-frags: per-iter direct from kTf (L2) --
// K never touches LDS. V: DMA double-buffered in 64 KB LDS (verified XOR swizzle).
// Fixed-offset softmax p = exp2(s - 36); l deferred; merge epilogue in 2 passes.
__global__ __launch_bounds__(512, 2)
void attn_kernel(const f16* __restrict__ qTf, const f16* __restrict__ kTf,
                 const f16* __restrict__ vW, const float* __restrict__ x,
                 float* __restrict__ out) {
    extern __shared__ unsigned char smem[];   // 66048: V dbuf 2x32768 + Ls 512

    const int b    = blockIdx.x & 7;          // batch -> XCD pinning for K/V L2 reuse
    const int i0   = (blockIdx.x >> 3) * 128;
    const int t    = threadIdx.x;
    const int w    = t >> 6;
    const int lane = t & 63;
    const int l31  = lane & 31;
    const int hi   = lane >> 5;
    const int iw   = (w & 3) * 32;            // i-strip
    const int jhw  = w >> 2;                  // j-half index
    const int jh8  = jhw * 4;
    const int it_i = (i0 >> 5) + (w & 3);
    const int xorv = l31 & 7;

    f16* Vs = (f16*)smem;
    float* Ls = (float*)(smem + 65536);

    // Q B-frags (coalesced 1KB frag loads, loop-invariant registers)
    f16x8 qf[16];
    {
        const f16* qb = qTf + ((size_t)(b * 128 + it_i) * 16) * 512 + lane * 8;
#pragma unroll
        for (int ks = 0; ks < 16; ++ks) qf[ks] = *(const f16x8*)(qb + ks * 512);
    }

    int vp2o[2];
#pragma unroll
    for (int kj = 0; kj < 2; ++kj) vp2o[kj] = l31 * 64 + (((jh8 + 2 * kj + hi) ^ xorv)) * 8;

    f32x16 acc[8];
#pragma unroll
    for (int ct = 0; ct < 8; ++ct)
#pragma unroll
        for (int r = 0; r < 16; ++r) acc[ct][r] = 0.0f;
    float lrun = 0.0f;

    const f16* vbg = vW + (size_t)b * CDIM * NPIX;
    const f16* kf0 = kTf + ((size_t)(b * 128 + jhw) * 16) * 512 + lane * 8;
    const int wub = (t & ~63) * 8;            // wave-uniform staging base (f16 units)

    // prologue: stage V tile 0 into buffer 0
#pragma unroll
    for (int rep = 0; rep < 4; ++rep) {
        int slot = t + rep * 512;
        int vrow = slot >> 3, vpc = slot & 7;
        gl2lds16(vbg + (size_t)vrow * NPIX + ((vpc ^ (vrow & 7)) * 8), Vs + wub + rep * 4096);
    }

#pragma unroll 1
    for (int jt = 0; jt < 64; ++jt) {
        const int p = jt & 1;
        __syncthreads();   // V buffer p landed (vmcnt drained); p^1 free to restage

        // K frags for this iter: direct from L2, no LDS
        const f16* kp = kf0 + (size_t)jt * 16384;
        f16x8 kf[16];
#pragma unroll
        for (int ks = 0; ks < 16; ++ks) kf[ks] = *(const f16x8*)(kp + ks * 512);

        // prefetch next V tile into p^1 (in flight across this whole compute phase)
        if (jt < 63) {
            const int j0n = (jt + 1) * 64;
            f16* dstb = Vs + (p ^ 1) * 16384;
#pragma unroll
            for (int rep = 0; rep < 4; ++rep) {
                int slot = t + rep * 512;
                int vrow = slot >> 3, vpc = slot & 7;
                gl2lds16(vbg + (size_t)vrow * NPIX + j0n + ((vpc ^ (vrow & 7)) * 8),
                         dstb + wub + rep * 4096);
            }
        }

        // S^T (32 j-half x 32 i) = K Q^T, C-init -SOFF folds the exp2 offset
        f32x16 s;
#pragma unroll
        for (int r = 0; r < 16; ++r) s[r] = -SOFF;
#pragma unroll
        for (int ks = 0; ks < 16; ++ks)
            s = __builtin_amdgcn_mfma_f32_32x32x16_f16(kf[ks], qf[ks], s, 0, 0, 0);

        // fixed-offset softmax numerator; row-sum deferred to epilogue
        Q4 ownq[4];
        float rtot = 0.0f;
#pragma unroll
        for (int g = 0; g < 4; ++g) {
            float p0 = __builtin_amdgcn_exp2f(s[4 * g + 0]);
            float p1 = __builtin_amdgcn_exp2f(s[4 * g + 1]);
            float p2 = __builtin_amdgcn_exp2f(s[4 * g + 2]);
            float p3 = __builtin_amdgcn_exp2f(s[4 * g + 3]);
            rtot += (p0 + p1) + (p2 + p3);
            ownq[g].h4[0] = (f16)p0; ownq[g].h4[1] = (f16)p1;
            ownq[g].h4[2] = (f16)p2; ownq[g].h4[3] = (f16)p3;
        }
        lrun += rtot;

        // P: C-layout -> B-layout via lane^32 quad exchange
        f16x8 pb0 = quad_exchange(ownq, 0, hi);
        f16x8 pb1 = quad_exchange(ownq, 1, hi);

        // O += V P^T  (A = V[c][j-half] from LDS buffer p)
        const f16* Vp = Vs + p * 16384;
#pragma unroll
        for (int ct = 0; ct < 8; ++ct) {
            acc[ct] = __builtin_amdgcn_mfma_f32_32x32x16_f16(
                *(const f16x8*)(Vp + vp2o[0] + ct * 2048), pb0, acc[ct], 0, 0, 0);
            acc[ct] = __builtin_amdgcn_mfma_f32_32x32x16_f16(
                *(const f16x8*)(Vp + vp2o[1] + ct * 2048), pb1, acc[ct], 0, 0, 0);
        }
    }

    // ---- epilogue: merge j-half pairs (w <-> w+4) in 2 passes (64 KB overlay) ----
    float lsum = lrun + __shfl_xor(lrun, 32);
    __syncthreads();
    if (w >= 4 && hi == 0) Ls[(w - 4) * 32 + l31] = lsum;
    __syncthreads();
    float invl = 0.0f;
    if (w < 4) invl = 1.0f / (lsum + Ls[w * 32 + l31]);

    float* Obuf = (float*)smem;               // 4 pairs x 128c x 32i fp32 = 64 KB per pass
#pragma unroll 1
    for (int pass = 0; pass < 2; ++pass) {
        if (w >= 4) {
            float* ob = Obuf + (w - 4) * 4096;
#pragma unroll
            for (int c4 = 0; c4 < 4; ++c4) {
                const int ct = pass * 4 + c4;
#pragma unroll
                for (int r = 0; r < 16; ++r) {
                    int cl = c4 * 32 + (r & 3) + 8 * (r >> 2) + 4 * hi;
                    ob[cl * 32 + l31] = acc[ct][r];
                }
            }
        }
        __syncthreads();
        if (w < 4) {
            const float* po = Obuf + w * 4096;
            const float* xb = x + (size_t)b * CDIM * NPIX + i0 + iw;
            float* og = out + (size_t)b * CDIM * NPIX + i0 + iw;
#pragma unroll
            for (int c4 = 0; c4 < 4; ++c4) {
                const int ct = pass * 4 + c4;
#pragma unroll
                for (int r = 0; r < 16; ++r) {
                    int cl = c4 * 32 + (r & 3) + 8 * (r >> 2) + 4 * hi;
                    int c  = ct * 32 + (r & 3) + 8 * (r >> 2) + 4 * hi;
                    size_t off = (size_t)c * NPIX + l31;
                    og[off] = (acc[ct][r] + po[cl * 32 + l31]) * invl + xb[off];
                }
            }
        }
        __syncthreads();
    }
}

extern "C" void kernel_launch(void* const* d_in, const int* in_sizes, int n_in,
                              void* d_out, int out_size, void* d_ws, size_t ws_size,
                              hipStream_t stream) {
    const float* x    = (const float*)d_in[0];
    const float* attr = (const float*)d_in[1];
    const float* Wq   = (const float*)d_in[2];
    const float* bq   = (const float*)d_in[3];
    const float* Wk   = (const float*)d_in[4];
    const float* bk   = (const float*)d_in[5];
    const float* Wv   = (const float*)d_in[6];
    const float* bv   = (const float*)d_in[7];
    float* out = (float*)d_out;

    // workspace layout (~48.4 MB)
    char* ws = (char*)d_ws;
    const size_t qkv_bytes = (size_t)8 * NPIX * CDIM * sizeof(f16);  // 16 MB each
    f16* qTf  = (f16*)ws;
    f16* kTf  = (f16*)(ws + qkv_bytes);
    f16* vW   = (f16*)(ws + 2 * qkv_bytes);
    f16* Wq_h = (f16*)(ws + 3 * qkv_bytes);
    f16* Wk_h = Wq_h + 65536;
    f16* Wv_h = Wk_h + 65536;

    (void)hipFuncSetAttribute((const void*)attn_kernel,
                              hipFuncAttributeMaxDynamicSharedMemorySize, 66048);

    convert_w_kernel<<<256, 256, 0, stream>>>(Wq, Wk, Wv, Wq_h, Wk_h, Wv_h);
    proj_kernel<<<512, 256, 0, stream>>>(x, attr, Wq_h, bq, Wk_h, bk, Wv_h, bv, qTf, kTf, vW);
    attn_kernel<<<256, 512, 66048, stream>>>(qTf, kTf, vW, x, out);
}